// Round 9
// baseline (645.177 us; speedup 1.0000x reference)
//
#include <hip/hip_runtime.h>
#include <cstdint>
#include <cstddef>

// ---------------------------------------------------------------------------
// MultiStageDiT round 9: gemm256 address strength-reduction. Same 8-phase
// schedule as round 8; all global stage addresses become persistent pointers
// (+=64/tile), LDS stage dests and ds_read fragment addresses become
// precomputed bases + compile-time immediates (swizzle decomposes:
// swz = (lane>>4)^(lane&7)^(ks<<2)). attn/tab/LN/prep unchanged.
// ---------------------------------------------------------------------------

typedef float  f32x4    __attribute__((ext_vector_type(4)));
typedef __bf16 bf16x8_t __attribute__((ext_vector_type(8)));
typedef __bf16 bf16x4_t __attribute__((ext_vector_type(4)));

#define DEV __device__ __forceinline__

DEV void gload_lds16(const void* g, void* l) {
    auto gp = (const uint32_t __attribute__((address_space(1)))*)(uintptr_t)g;
    auto lp = (uint32_t __attribute__((address_space(3)))*)(uint32_t)(uintptr_t)l;
    __builtin_amdgcn_global_load_lds(gp, lp, 16, 0, 0);
}

// row-major LDS tile, 16B chunks XOR-swizzled by (row&7)
DEV bf16x8_t lds_frag(const __bf16* base, int row, int chunk, int row_elems) {
    return *(const bf16x8_t*)(base + row * row_elems + ((chunk ^ (row & 7)) << 3));
}

// 32-elem-row P tile: XOR key (row>>1)&3
DEV bf16x8_t p_frag(const __bf16* base, int row, int chunk) {
    return *(const bf16x8_t*)(base + row * 32 + ((chunk ^ ((row >> 1) & 3)) << 3));
}

// V^T tile elem address: key (d&7)^((d>>3)&7)
DEV int vt_addr(int d, int k) {
    return d * 64 + ((((k >> 3) ^ (d & 7) ^ ((d >> 3) & 7)) << 3) | (k & 7));
}

DEV float gelu_tanh(float v) {
    float u = 0.7978845608028654f * (v + 0.044715f * v * v * v);
    float e = __expf(2.f * u);
    float th = 1.f - 2.f / (e + 1.f);
    return 0.5f * v * (1.f + th);
}

DEV int win2tok(int r) {
    int nb = r >> 12, wi = (r >> 8) & 15, l = r & 255;
    return (nb << 12) + (wi >> 2) * 1024 + (l >> 4) * 64 + (wi & 3) * 16 + (l & 15);
}

// ---------------------------------------------------------------------------
// prep kernels
// ---------------------------------------------------------------------------
__global__ void silu_k(const float* __restrict__ c, float* __restrict__ o, int n) {
    int i = blockIdx.x * 256 + threadIdx.x;
    if (i < n) { float v = c[i]; o[i] = v / (1.f + __expf(-v)); }
}

__global__ void zero_k(float* o, int n) {
    int i = blockIdx.x * 256 + threadIdx.x;
    if (i < n) o[i] = 0.f;
}

__global__ void conv_bf16(const float* __restrict__ s, __bf16* __restrict__ d, int n4) {
    int i = blockIdx.x * 256 + threadIdx.x;
    if (i < n4) {
        float4 v = ((const float4*)s)[i];
        bf16x4_t o; o[0] = (__bf16)v.x; o[1] = (__bf16)v.y; o[2] = (__bf16)v.z; o[3] = (__bf16)v.w;
        ((bf16x4_t*)d)[i] = o;
    }
}

__global__ __launch_bounds__(256)
void mod_gemv(const float* __restrict__ sc, const float* __restrict__ w,
              const float* __restrict__ b, float* __restrict__ mod) {
    int o = (blockIdx.x << 2) + (threadIdx.x >> 6);
    int lane = threadIdx.x & 63;
    int n = o / 6144, col = o % 6144;
    const float4* wr = (const float4*)(w + (size_t)col * 1024);
    const float4* sr = (const float4*)(sc + n * 1024);
    float acc = 0.f;
    #pragma unroll 4
    for (int i = lane; i < 256; i += 64) {
        float4 a = wr[i], x = sr[i];
        acc += a.x * x.x + a.y * x.y + a.z * x.z + a.w * x.w;
    }
    #pragma unroll
    for (int m = 1; m < 64; m <<= 1) acc += __shfl_xor(acc, m);
    if (lane == 0) mod[o] = acc + b[col];
}

__global__ __launch_bounds__(256)
void ln_mod_k(const float* __restrict__ src, const float* __restrict__ mod,
              int sh_off, int sc_off, __bf16* __restrict__ out, int permute, int r0) {
    int rl = blockIdx.x;
    int r = rl + r0;
    int nb = r >> 12;
    int t = permute ? win2tok(r) : r;
    float4 v = ((const float4*)(src + (size_t)t * 1024))[threadIdx.x];
    float s  = v.x + v.y + v.z + v.w;
    float sq = v.x * v.x + v.y * v.y + v.z * v.z + v.w * v.w;
    #pragma unroll
    for (int m = 1; m < 64; m <<= 1) { s += __shfl_xor(s, m); sq += __shfl_xor(sq, m); }
    __shared__ float ps[4], pq[4];
    int wv = threadIdx.x >> 6, ln = threadIdx.x & 63;
    if (ln == 0) { ps[wv] = s; pq[wv] = sq; }
    __syncthreads();
    s  = ps[0] + ps[1] + ps[2] + ps[3];
    sq = pq[0] + pq[1] + pq[2] + pq[3];
    float mean = s * (1.f / 1024.f);
    float var  = sq * (1.f / 1024.f) - mean * mean;
    float rstd = rsqrtf(var + 1e-6f);
    int c = threadIdx.x << 2;
    const float* mrow = mod + nb * 6144;
    float4 scv = *(const float4*)(mrow + sc_off + c);
    float4 shv = *(const float4*)(mrow + sh_off + c);
    bf16x4_t o;
    o[0] = (__bf16)((v.x - mean) * rstd * (1.f + scv.x) + shv.x);
    o[1] = (__bf16)((v.y - mean) * rstd * (1.f + scv.y) + shv.y);
    o[2] = (__bf16)((v.z - mean) * rstd * (1.f + scv.z) + shv.z);
    o[3] = (__bf16)((v.w - mean) * rstd * (1.f + scv.w) + shv.w);
    *(bf16x4_t*)(out + (size_t)rl * 1024 + c) = o;
}

// ---------------------------------------------------------------------------
// 256x256 8-phase bf16 GEMM, strength-reduced addressing.
// Schedule identical to round 8 (passing): per phase reads+stage, GBAR,
// lgkmcnt(0), setprio MFMA cluster, GBAR; vmcnt(6) once per tile boundary.
// ---------------------------------------------------------------------------
template <int PM, int PN>
DEV void mfma16(f32x4 (&acc)[8][4], bf16x8_t (&fa)[4][2], bf16x8_t (&fb)[2][2][2]) {
    #pragma unroll
    for (int ks = 0; ks < 2; ++ks)
        #pragma unroll
        for (int mi = 0; mi < 4; ++mi)
            #pragma unroll
            for (int nn = 0; nn < 2; ++nn)
                acc[PM * 4 + mi][PN * 2 + nn] = __builtin_amdgcn_mfma_f32_16x16x32_bf16(
                    fa[mi][ks], fb[PN][nn][ks], acc[PM * 4 + mi][PN * 2 + nn], 0, 0, 0);
}

#define GBAR  __builtin_amdgcn_s_barrier()
#define LGKM0 do { asm volatile("s_waitcnt lgkmcnt(0)" ::: "memory"); \
                   __builtin_amdgcn_sched_barrier(0); } while (0)
#define PRIO1 __builtin_amdgcn_s_setprio(1)
#define PRIO0 __builtin_amdgcn_s_setprio(0)

template <int EPI>
__global__ __launch_bounds__(512)
void gemm256(const __bf16* __restrict__ A, const __bf16* __restrict__ B,
             const float* __restrict__ bias, void* __restrict__ Cout,
             const float* __restrict__ extra, const float* __restrict__ mod,
             int N, int K, int r0, int gx) {
    extern __shared__ __align__(16) char smem[];
    __bf16* lA = (__bf16*)smem;             // [2][256*64]
    __bf16* lB = lA + 2 * 16384;            // [2][256*64]
    const int tid = threadIdx.x, lane = tid & 63, wv = tid >> 6;
    const int wr = wv >> 2, wc = wv & 3;

    // bijective XCD-aware block swizzle (1-D grid)
    const int nwg = gridDim.x;
    const int qq = nwg >> 3, rr8 = nwg & 7;
    const int xcd = blockIdx.x & 7, pos = blockIdx.x >> 3;
    const int nid = (xcd < rr8 ? xcd * (qq + 1) : rr8 * (qq + 1) + (xcd - rr8) * qq) + pos;
    const int bm = (nid / gx) << 8, bn = (nid % gx) << 8;

    f32x4 acc[8][4];
    const f32x4 z4 = {0.f, 0.f, 0.f, 0.f};
    #pragma unroll
    for (int i = 0; i < 8; ++i)
        #pragma unroll
        for (int j = 0; j < 4; ++j) acc[i][j] = z4;

    bf16x8_t fa[4][2], fb[2][2][2];

    // ---- persistent stage pointers (advance +=64 once per tile each) ----
    const int l8  = lane >> 3;
    const int gc8 = ((lane & 7) ^ l8) << 3;
    const int rbw = ((wv & 3) << 3) + ((wv >> 2) << 6);
    const __bf16* gA0 = A + (size_t)(bm +       (wv << 3) + l8) * K + gc8;
    const __bf16* gA1 = A + (size_t)(bm + 128 + (wv << 3) + l8) * K + gc8;
    const __bf16* gA2 = A + (size_t)(bm +  64 + (wv << 3) + l8) * K + gc8;
    const __bf16* gA3 = A + (size_t)(bm + 192 + (wv << 3) + l8) * K + gc8;
    const __bf16* gB0 = B + (size_t)(bn +       rbw + l8) * K + gc8;
    const __bf16* gB1 = B + (size_t)(bn + 128 + rbw + l8) * K + gc8;
    const __bf16* gB2 = B + (size_t)(bn +  32 + rbw + l8) * K + gc8;
    const __bf16* gB3 = B + (size_t)(bn + 160 + rbw + l8) * K + gc8;
    // LDS stage dest element offsets (wave-uniform)
    const int dA0 = (wv << 3) * 64, dA1 = (128 + (wv << 3)) * 64;
    const int dA2 = (64 + (wv << 3)) * 64, dA3 = (192 + (wv << 3)) * 64;
    const int dB0 = rbw * 64, dB1 = (128 + rbw) * 64;
    const int dB2 = (32 + rbw) * 64, dB3 = (160 + rbw) * 64;

    auto stA0 = [&](int be) { gload_lds16(gA0, lA + be + dA0); gload_lds16(gA1, lA + be + dA1); gA0 += 64; gA1 += 64; };
    auto stA1 = [&](int be) { gload_lds16(gA2, lA + be + dA2); gload_lds16(gA3, lA + be + dA3); gA2 += 64; gA3 += 64; };
    auto stB0 = [&](int be) { gload_lds16(gB0, lB + be + dB0); gload_lds16(gB1, lB + be + dB1); gB0 += 64; gB1 += 64; };
    auto stB1 = [&](int be) { gload_lds16(gB2, lB + be + dB2); gload_lds16(gB3, lB + be + dB3); gB2 += 64; gB3 += 64; };

    // ---- precomputed ds_read fragment bases ----
    // frag addr = base_ks + bufe + pm*4096 + mi*1024 (A) / pn*2048 + ni*1024 (B)
    const int swzb = (lane >> 4) ^ (lane & 7);
    const __bf16* aR0 = lA + (wr << 13) + ((lane & 15) << 6) + (swzb << 3);
    const __bf16* aR1 = lA + (wr << 13) + ((lane & 15) << 6) + ((swzb ^ 4) << 3);
    const __bf16* bR0 = lB + (wc << 12) + ((lane & 15) << 6) + (swzb << 3);
    const __bf16* bR1 = lB + (wc << 12) + ((lane & 15) << 6) + ((swzb ^ 4) << 3);

    auto readA = [&](int be, int pm) {
        #pragma unroll
        for (int mi = 0; mi < 4; ++mi) {
            fa[mi][0] = *(const bf16x8_t*)(aR0 + be + pm * 4096 + mi * 1024);
            fa[mi][1] = *(const bf16x8_t*)(aR1 + be + pm * 4096 + mi * 1024);
        }
    };
    auto readB = [&](int be, int pn) {
        #pragma unroll
        for (int ni = 0; ni < 2; ++ni) {
            fb[pn][ni][0] = *(const bf16x8_t*)(bR0 + be + pn * 2048 + ni * 1024);
            fb[pn][ni][1] = *(const bf16x8_t*)(bR1 + be + pn * 2048 + ni * 1024);
        }
    };

    const int nt = K >> 6;
    // prologue: tile0 full + tile1 A0,B0,B1 (A1 of t1 staged at ph0 of t0)
    stA0(0); stB0(0); stB1(0); stA1(0);
    stA0(16384); stB0(16384); stB1(16384);
    asm volatile("s_waitcnt vmcnt(6)" ::: "memory");
    GBAR;

    int be = 0;
    for (int t = 0; t < nt - 1; ++t) {
        const bool s2 = (t + 2 < nt);
        // ---- phase 0: read A0,B0(cur); stage A1(t+1) -> other buf ----
        readA(be, 0); readB(be, 0);
        stA1(be ^ 16384);
        GBAR; LGKM0;
        PRIO1; mfma16<0, 0>(acc, fa, fb); PRIO0;
        GBAR;
        // ---- phase 1: read B1(cur); stage A0(t+2) -> same-parity buf ----
        readB(be, 1);
        if (s2) stA0(be);
        GBAR; LGKM0;
        PRIO1; mfma16<0, 1>(acc, fa, fb); PRIO0;
        GBAR;
        // ---- phase 2: read A1(cur); stage B0(t+2) ----
        readA(be, 1);
        if (s2) stB0(be);
        GBAR; LGKM0;
        PRIO1; mfma16<1, 0>(acc, fa, fb); PRIO0;
        GBAR;
        // ---- phase 3: stage B1(t+2); boundary vmcnt ----
        if (s2) stB1(be);
        if (t == nt - 2) asm volatile("s_waitcnt vmcnt(0)" ::: "memory");
        else             asm volatile("s_waitcnt vmcnt(6)" ::: "memory");
        GBAR;
        PRIO1; mfma16<1, 1>(acc, fa, fb); PRIO0;
        GBAR;
        be ^= 16384;
    }
    // ---- tail tile (certified by final vmcnt(0)) ----
    readA(be, 0); readB(be, 0); readB(be, 1);
    LGKM0;
    PRIO1; mfma16<0, 0>(acc, fa, fb); mfma16<0, 1>(acc, fa, fb); PRIO0;
    readA(be, 1);
    LGKM0;
    PRIO1; mfma16<1, 0>(acc, fa, fb); mfma16<1, 1>(acc, fa, fb); PRIO0;

    // ---- epilogue ----
    #pragma unroll
    for (int am = 0; am < 8; ++am) {
        #pragma unroll
        for (int j = 0; j < 4; ++j) {
            int m = bm + (wr << 7) + (am << 4) + ((lane >> 4) << 2) + j;
            #pragma unroll
            for (int an = 0; an < 4; ++an) {
                int n = bn + (wc << 6) + (an << 4) + (lane & 15);
                float v = acc[am][an][j] + bias[n];
                if constexpr (EPI == 0) {
                    ((__bf16*)Cout)[(size_t)m * N + n] = (__bf16)v;
                } else if constexpr (EPI == 1) {
                    int mg = m + r0;
                    int tr = win2tok(mg);
                    float g = mod[(mg >> 12) * 6144 + 2048 + n];
                    ((float*)Cout)[(size_t)tr * 1024 + n] = extra[(size_t)tr * 1024 + n] + g * v;
                } else if constexpr (EPI == 2) {
                    ((__bf16*)Cout)[(size_t)m * N + n] = (__bf16)gelu_tanh(v);
                } else {
                    int mg = m + r0;
                    float g = mod[(mg >> 12) * 6144 + 5120 + n];
                    ((float*)Cout)[(size_t)mg * 1024 + n] = extra[(size_t)mg * 1024 + n] + g * v;
                }
            }
        }
    }
}

// ---------------------------------------------------------------------------
// Rel-pos bias tables (LDS-staged rel matrices) — unchanged.
// ---------------------------------------------------------------------------
__global__ __launch_bounds__(256)
void tab_k(const __bf16* __restrict__ qkv, const float* __restrict__ relh,
           const float* __restrict__ relw, __bf16* __restrict__ tab) {
    __shared__ __bf16 lR[2][31][72];
    for (int i = threadIdx.x; i < 1984; i += 256) {
        int row = i >> 6, c = i & 63;
        lR[0][row][c] = (__bf16)relh[i];
        lR[1][row][c] = (__bf16)relw[i];
    }
    __syncthreads();
    const int h = blockIdx.y;
    const int r = threadIdx.x >> 1, half = threadIdx.x & 1;
    const int l = blockIdx.x * 128 + r;
    const int lw = l & 255;
    const int qi = lw >> 4, qj = lw & 15;
    const __bf16* qrow = qkv + (size_t)l * 3072 + h * 64;
    float qq[64];
    #pragma unroll
    for (int c8 = 0; c8 < 8; ++c8) {
        bf16x8_t q8 = *(const bf16x8_t*)(qrow + (c8 << 3));
        #pragma unroll
        for (int e = 0; e < 8; ++e) qq[c8 * 8 + e] = (float)q8[e];
    }
    bf16x8_t oh, ow;
    #pragma unroll
    for (int kk = 0; kk < 8; ++kk) {
        int kg = (half << 3) + kk;
        const __bf16* Rh = &lR[0][qi - kg + 15][0];
        const __bf16* Rw = &lR[1][qj - kg + 15][0];
        float ah = 0.f, aw = 0.f;
        #pragma unroll
        for (int c8 = 0; c8 < 8; ++c8) {
            bf16x8_t r1 = *(const bf16x8_t*)(Rh + (c8 << 3));
            bf16x8_t r2 = *(const bf16x8_t*)(Rw + (c8 << 3));
            #pragma unroll
            for (int e = 0; e < 8; ++e) {
                ah += qq[c8 * 8 + e] * (float)r1[e];
                aw += qq[c8 * 8 + e] * (float)r2[e];
            }
        }
        oh[kk] = (__bf16)ah; ow[kk] = (__bf16)aw;
    }
    size_t idx = ((size_t)(l >> 8) * 16 + h) * 256 + lw;
    *(bf16x8_t*)(tab + idx * 32 + (half << 3))      = oh;
    *(bf16x8_t*)(tab + idx * 32 + 16 + (half << 3)) = ow;
}

// ---------------------------------------------------------------------------
// Window attention — unchanged (passing).
// ---------------------------------------------------------------------------
__global__ __launch_bounds__(256, 3)
void attn_k(const __bf16* __restrict__ qkv, const __bf16* __restrict__ tab,
            __bf16* __restrict__ out) {
    __shared__ __align__(16) __bf16 lP[4][32 * 32];
    __shared__ __align__(16) __bf16 lKt[2][64 * 64];
    __shared__ __align__(16) __bf16 lVt[2][64 * 64];
    __shared__ __align__(16) __bf16 lTab[128 * 32];

    const int blk = blockIdx.x;
    const int winc = blk >> 5, h = (blk >> 1) & 15, qh = blk & 1;
    const int tid = threadIdx.x, lane = tid & 63, wv = tid >> 6;
    const __bf16* base = qkv + (size_t)winc * 256 * 3072 + h * 64;
    const int q0 = qh << 7;

    {
        const __bf16* ts = tab + (((size_t)winc * 16 + h) * 256 + q0) * 32;
        #pragma unroll
        for (int q = 0; q < 2; ++q) {
            int c = (wv << 1) + q;
            gload_lds16(ts + c * 512 + lane * 8, lTab + c * 512);
        }
    }
    bf16x8_t qf[2][2];
    #pragma unroll
    for (int mi = 0; mi < 2; ++mi)
        #pragma unroll
        for (int ks = 0; ks < 2; ++ks) {
            int l = q0 + (wv << 5) + (mi << 4) + (lane & 15);
            qf[mi][ks] = *(const bf16x8_t*)(base + (size_t)l * 3072 + (((ks << 2) + (lane >> 4)) << 3));
        }
    {
        const __bf16* kb = base + 1024;
        #pragma unroll
        for (int q = 0; q < 2; ++q) {
            int c = (wv << 1) + q;
            int kl = (c << 3) + (lane >> 3);
            gload_lds16(kb + (size_t)kl * 3072 + (((lane & 7) ^ (lane >> 3)) << 3),
                        lKt[0] + c * 512);
        }
        const __bf16* vb = base + 2048;
        bf16x8_t a = *(const bf16x8_t*)(vb + (size_t)(tid >> 3) * 3072 + ((tid & 7) << 3));
        bf16x8_t b = *(const bf16x8_t*)(vb + (size_t)(32 + (tid >> 3)) * 3072 + ((tid & 7) << 3));
        int lc = tid & 7;
        #pragma unroll
        for (int e = 0; e < 8; ++e) {
            lVt[0][vt_addr(lc * 8 + e, tid >> 3)]        = a[e];
            lVt[0][vt_addr(lc * 8 + e, 32 + (tid >> 3))] = b[e];
        }
    }
    __syncthreads();

    float twv[2][4];
    #pragma unroll
    for (int mi = 0; mi < 2; ++mi)
        #pragma unroll
        for (int j = 0; j < 4; ++j) {
            int qr = (wv << 5) + (mi << 4) + ((lane >> 4) << 2) + j;
            twv[mi][j] = (float)lTab[qr * 32 + 16 + (lane & 15)];
        }

    const f32x4 z4 = {0.f, 0.f, 0.f, 0.f};
    f32x4 oacc[2][4];
    #pragma unroll
    for (int a = 0; a < 2; ++a)
        #pragma unroll
        for (int b = 0; b < 4; ++b) oacc[a][b] = z4;
    float rsum[2][4];
    #pragma unroll
    for (int a = 0; a < 2; ++a)
        #pragma unroll
        for (int j = 0; j < 4; ++j) rsum[a][j] = 0.f;
    __bf16* lPw = lP[wv];

    int cur = 0;
    for (int kt = 0; kt < 4; ++kt) {
        const bool pre = (kt < 3);
        bf16x8_t v8a, v8b;
        if (pre) {
            const __bf16* kb = base + 1024 + (size_t)(kt + 1) * 64 * 3072;
            #pragma unroll
            for (int q = 0; q < 2; ++q) {
                int c = (wv << 1) + q;
                int kl = (c << 3) + (lane >> 3);
                gload_lds16(kb + (size_t)kl * 3072 + (((lane & 7) ^ (lane >> 3)) << 3),
                            lKt[cur ^ 1] + c * 512);
            }
            const __bf16* vb = base + 2048 + (size_t)(kt + 1) * 64 * 3072;
            v8a = *(const bf16x8_t*)(vb + (size_t)(tid >> 3) * 3072 + ((tid & 7) << 3));
            v8b = *(const bf16x8_t*)(vb + (size_t)(32 + (tid >> 3)) * 3072 + ((tid & 7) << 3));
        }

        f32x4 s[2][4];
        #pragma unroll
        for (int a = 0; a < 2; ++a)
            #pragma unroll
            for (int b = 0; b < 4; ++b) s[a][b] = z4;
        #pragma unroll
        for (int ks = 0; ks < 2; ++ks) {
            bf16x8_t kf[4];
            #pragma unroll
            for (int ni = 0; ni < 4; ++ni)
                kf[ni] = lds_frag(lKt[cur], (ni << 4) + (lane & 15), (ks << 2) + (lane >> 4), 64);
            #pragma unroll
            for (int mi = 0; mi < 2; ++mi)
                #pragma unroll
                for (int ni = 0; ni < 4; ++ni)
                    s[mi][ni] = __builtin_amdgcn_mfma_f32_16x16x32_bf16(qf[mi][ks], kf[ni], s[mi][ni], 0, 0, 0);
        }

        #pragma unroll
        for (int mi = 0; mi < 2; ++mi) {
            #pragma unroll
            for (int j = 0; j < 4; ++j) {
                int qr = (wv << 5) + (mi << 4) + ((lane >> 4) << 2) + j;
                bf16x4_t th4 = *(const bf16x4_t*)(lTab + qr * 32 + (kt << 2));
                float rs = 0.f;
                #pragma unroll
                for (int ni = 0; ni < 4; ++ni) {
                    float p = __expf(s[mi][ni][j] * 0.125f + (float)th4[ni] + twv[mi][j]);
                    s[mi][ni][j] = p;
                    rs += p;
                }
                rsum[mi][j] += rs;
            }
        }

        #pragma unroll
        for (int hf = 0; hf < 2; ++hf) {
            #pragma unroll
            for (int mi = 0; mi < 2; ++mi) {
                #pragma unroll
                for (int j = 0; j < 4; ++j) {
                    int rl = (mi << 4) + ((lane >> 4) << 2) + j;
                    #pragma unroll
                    for (int b = 0; b < 2; ++b) {
                        int col = (b << 4) + (lane & 15);
                        lPw[rl * 32 + ((((col >> 3) ^ ((rl >> 1) & 3)) << 3) | (col & 7))] =
                            (__bf16)s[mi][(hf << 1) + b][j];
                    }
                }
            }
            bf16x8_t pf[2], vf[4];
            #pragma unroll
            for (int mi = 0; mi < 2; ++mi)
                pf[mi] = p_frag(lPw, (mi << 4) + (lane & 15), lane >> 4);
            #pragma unroll
            for (int no = 0; no < 4; ++no) {
                int d = (no << 4) + (lane & 15);
                vf[no] = *(const bf16x8_t*)(lVt[cur] + vt_addr(d, ((hf << 2) + (lane >> 4)) << 3));
            }
            #pragma unroll
            for (int mi = 0; mi < 2; ++mi)
                #pragma unroll
                for (int no = 0; no < 4; ++no)
                    oacc[mi][no] = __builtin_amdgcn_mfma_f32_16x16x32_bf16(pf[mi], vf[no], oacc[mi][no], 0, 0, 0);
        }

        if (pre) {
            int lc = tid & 7;
            #pragma unroll
            for (int e = 0; e < 8; ++e) {
                lVt[cur ^ 1][vt_addr(lc * 8 + e, tid >> 3)]        = v8a[e];
                lVt[cur ^ 1][vt_addr(lc * 8 + e, 32 + (tid >> 3))] = v8b[e];
            }
        }
        __syncthreads();
        cur ^= 1;
    }

    #pragma unroll
    for (int mi = 0; mi < 2; ++mi) {
        #pragma unroll
        for (int j = 0; j < 4; ++j) {
            float rs = rsum[mi][j];
            #pragma unroll
            for (int msk = 1; msk < 16; msk <<= 1) rs += __shfl_xor(rs, msk);
            float inv = 1.f / rs;
            int l = q0 + (wv << 5) + (mi << 4) + ((lane >> 4) << 2) + j;
            #pragma unroll
            for (int no = 0; no < 4; ++no) {
                int col = (no << 4) + (lane & 15);
                out[(size_t)(winc * 256 + l) * 1024 + h * 64 + col] = (__bf16)(oacc[mi][no][j] * inv);
            }
        }
    }
}

// ---------------------------------------------------------------------------
extern "C" void kernel_launch(void* const* d_in, const int* in_sizes, int n_in,
                              void* d_out, int out_size, void* d_ws, size_t ws_size,
                              hipStream_t stream) {
    const float* x      = (const float*)d_in[0];
    const float* c      = (const float*)d_in[1];
    const float* qkv_w  = (const float*)d_in[2];
    const float* qkv_b  = (const float*)d_in[3];
    const float* proj_w = (const float*)d_in[4];
    const float* proj_b = (const float*)d_in[5];
    const float* rel_h  = (const float*)d_in[6];
    const float* rel_w  = (const float*)d_in[7];
    const float* ada_w  = (const float*)d_in[8];
    const float* ada_b  = (const float*)d_in[9];
    const float* fc1_w  = (const float*)d_in[10];
    const float* fc1_b  = (const float*)d_in[11];
    const float* fc2_w  = (const float*)d_in[12];
    const float* fc2_b  = (const float*)d_in[13];
    float* xo = (float*)d_out;

    char* ws = (char*)d_ws;
    const size_t MB = 1ull << 20;
    int CH = 0;
    const int cands[7] = {16384, 8192, 4096, 2048, 1024, 512, 256};
    for (int i = 0; i < 7; ++i)
        if (26 * MB + (size_t)cands[i] * 10240 <= ws_size) { CH = cands[i]; break; }
    if (CH == 0) {
        zero_k<<<65536, 256, 0, stream>>>(xo, 16777216);
        return;
    }

    const int LDSB = 131072;
    hipFuncSetAttribute((const void*)&gemm256<0>, hipFuncAttributeMaxDynamicSharedMemorySize, LDSB);
    hipFuncSetAttribute((const void*)&gemm256<1>, hipFuncAttributeMaxDynamicSharedMemorySize, LDSB);
    hipFuncSetAttribute((const void*)&gemm256<2>, hipFuncAttributeMaxDynamicSharedMemorySize, LDSB);
    hipFuncSetAttribute((const void*)&gemm256<3>, hipFuncAttributeMaxDynamicSharedMemorySize, LDSB);

    const int NCH = 16384 / CH;
    float*  ws_silu = (float*)(ws);
    float*  ws_mod  = (float*)(ws + 65536);
    __bf16* w_qkv   = (__bf16*)(ws + 1 * MB);
    __bf16* w_proj  = (__bf16*)(ws + 7 * MB);
    __bf16* w_fc1   = (__bf16*)(ws + 9 * MB);
    __bf16* w_fc2   = (__bf16*)(ws + 17 * MB);
    __bf16* bufA    = (__bf16*)(ws + 26 * MB);
    __bf16* bufB    = (__bf16*)(ws + 26 * MB + (size_t)CH * 2048);
    __bf16* tabbuf  = bufB + (size_t)CH * 3072;

    silu_k   <<<16,   256, 0, stream>>>(c, ws_silu, 4096);
    mod_gemv <<<6144, 256, 0, stream>>>(ws_silu, ada_w, ada_b, ws_mod);
    conv_bf16<<<3072, 256, 0, stream>>>(qkv_w,  w_qkv,  786432);
    conv_bf16<<<1024, 256, 0, stream>>>(proj_w, w_proj, 262144);
    conv_bf16<<<4096, 256, 0, stream>>>(fc1_w,  w_fc1,  1048576);
    conv_bf16<<<4096, 256, 0, stream>>>(fc2_w,  w_fc2,  1048576);

    const int gy = CH / 256;
    for (int ci = 0; ci < NCH; ++ci) {
        int r0 = ci * CH;
        ln_mod_k<<<CH, 256, 0, stream>>>(x, ws_mod, 0, 1024, bufA, 1, r0);
        gemm256<0><<<12 * gy, 512, LDSB, stream>>>(bufA, w_qkv, qkv_b, bufB,
                                                   nullptr, nullptr, 3072, 1024, r0, 12);
        tab_k<<<dim3(CH / 128, 16), 256, 0, stream>>>(bufB, rel_h, rel_w, tabbuf);
        attn_k<<<(CH / 256) * 32, 256, 0, stream>>>(bufB, tabbuf, bufA);
        gemm256<1><<<4 * gy, 512, LDSB, stream>>>(bufA, w_proj, proj_b, xo,
                                                  x, ws_mod, 1024, 1024, r0, 4);
    }
    for (int ci = 0; ci < NCH; ++ci) {
        int r0 = ci * CH;
        ln_mod_k<<<CH, 256, 0, stream>>>(xo, ws_mod, 3072, 4096, bufA, 0, r0);
        gemm256<2><<<16 * gy, 512, LDSB, stream>>>(bufA, w_fc1, fc1_b, bufB,
                                                   nullptr, nullptr, 4096, 1024, r0, 16);
        gemm256<3><<<4 * gy, 512, LDSB, stream>>>(bufB, w_fc2, fc2_b, xo,
                                                  xo, ws_mod, 1024, 4096, r0, 4);
    }
}

// Round 10
// 631.514 us; speedup vs baseline: 1.0216x; 1.0216x over previous
//
#include <hip/hip_runtime.h>
#include <cstdint>
#include <cstddef>

// ---------------------------------------------------------------------------
// MultiStageDiT round 10: gemm256 = round-7 flow (best measured: 1 barrier/
// phase, per-phase vmcnt(6), strict next-tile staging -> no WAR) + round-9
// strength-reduced addressing, WITH the lgkmcnt(0)+sched_barrier pins REMOVED
// (compiler-emitted ds_reads get fine-grained lgkm interleave with MFMA).
// attn/tab/LN/prep unchanged.
// ---------------------------------------------------------------------------

typedef float  f32x4    __attribute__((ext_vector_type(4)));
typedef __bf16 bf16x8_t __attribute__((ext_vector_type(8)));
typedef __bf16 bf16x4_t __attribute__((ext_vector_type(4)));

#define DEV __device__ __forceinline__

DEV void gload_lds16(const void* g, void* l) {
    auto gp = (const uint32_t __attribute__((address_space(1)))*)(uintptr_t)g;
    auto lp = (uint32_t __attribute__((address_space(3)))*)(uint32_t)(uintptr_t)l;
    __builtin_amdgcn_global_load_lds(gp, lp, 16, 0, 0);
}

// row-major LDS tile, 16B chunks XOR-swizzled by (row&7)
DEV bf16x8_t lds_frag(const __bf16* base, int row, int chunk, int row_elems) {
    return *(const bf16x8_t*)(base + row * row_elems + ((chunk ^ (row & 7)) << 3));
}

// 32-elem-row P tile: XOR key (row>>1)&3
DEV bf16x8_t p_frag(const __bf16* base, int row, int chunk) {
    return *(const bf16x8_t*)(base + row * 32 + ((chunk ^ ((row >> 1) & 3)) << 3));
}

// V^T tile elem address: key (d&7)^((d>>3)&7)
DEV int vt_addr(int d, int k) {
    return d * 64 + ((((k >> 3) ^ (d & 7) ^ ((d >> 3) & 7)) << 3) | (k & 7));
}

DEV float gelu_tanh(float v) {
    float u = 0.7978845608028654f * (v + 0.044715f * v * v * v);
    float e = __expf(2.f * u);
    float th = 1.f - 2.f / (e + 1.f);
    return 0.5f * v * (1.f + th);
}

DEV int win2tok(int r) {
    int nb = r >> 12, wi = (r >> 8) & 15, l = r & 255;
    return (nb << 12) + (wi >> 2) * 1024 + (l >> 4) * 64 + (wi & 3) * 16 + (l & 15);
}

// ---------------------------------------------------------------------------
// prep kernels
// ---------------------------------------------------------------------------
__global__ void silu_k(const float* __restrict__ c, float* __restrict__ o, int n) {
    int i = blockIdx.x * 256 + threadIdx.x;
    if (i < n) { float v = c[i]; o[i] = v / (1.f + __expf(-v)); }
}

__global__ void zero_k(float* o, int n) {
    int i = blockIdx.x * 256 + threadIdx.x;
    if (i < n) o[i] = 0.f;
}

__global__ void conv_bf16(const float* __restrict__ s, __bf16* __restrict__ d, int n4) {
    int i = blockIdx.x * 256 + threadIdx.x;
    if (i < n4) {
        float4 v = ((const float4*)s)[i];
        bf16x4_t o; o[0] = (__bf16)v.x; o[1] = (__bf16)v.y; o[2] = (__bf16)v.z; o[3] = (__bf16)v.w;
        ((bf16x4_t*)d)[i] = o;
    }
}

__global__ __launch_bounds__(256)
void mod_gemv(const float* __restrict__ sc, const float* __restrict__ w,
              const float* __restrict__ b, float* __restrict__ mod) {
    int o = (blockIdx.x << 2) + (threadIdx.x >> 6);
    int lane = threadIdx.x & 63;
    int n = o / 6144, col = o % 6144;
    const float4* wr = (const float4*)(w + (size_t)col * 1024);
    const float4* sr = (const float4*)(sc + n * 1024);
    float acc = 0.f;
    #pragma unroll 4
    for (int i = lane; i < 256; i += 64) {
        float4 a = wr[i], x = sr[i];
        acc += a.x * x.x + a.y * x.y + a.z * x.z + a.w * x.w;
    }
    #pragma unroll
    for (int m = 1; m < 64; m <<= 1) acc += __shfl_xor(acc, m);
    if (lane == 0) mod[o] = acc + b[col];
}

__global__ __launch_bounds__(256)
void ln_mod_k(const float* __restrict__ src, const float* __restrict__ mod,
              int sh_off, int sc_off, __bf16* __restrict__ out, int permute, int r0) {
    int rl = blockIdx.x;
    int r = rl + r0;
    int nb = r >> 12;
    int t = permute ? win2tok(r) : r;
    float4 v = ((const float4*)(src + (size_t)t * 1024))[threadIdx.x];
    float s  = v.x + v.y + v.z + v.w;
    float sq = v.x * v.x + v.y * v.y + v.z * v.z + v.w * v.w;
    #pragma unroll
    for (int m = 1; m < 64; m <<= 1) { s += __shfl_xor(s, m); sq += __shfl_xor(sq, m); }
    __shared__ float ps[4], pq[4];
    int wv = threadIdx.x >> 6, ln = threadIdx.x & 63;
    if (ln == 0) { ps[wv] = s; pq[wv] = sq; }
    __syncthreads();
    s  = ps[0] + ps[1] + ps[2] + ps[3];
    sq = pq[0] + pq[1] + pq[2] + pq[3];
    float mean = s * (1.f / 1024.f);
    float var  = sq * (1.f / 1024.f) - mean * mean;
    float rstd = rsqrtf(var + 1e-6f);
    int c = threadIdx.x << 2;
    const float* mrow = mod + nb * 6144;
    float4 scv = *(const float4*)(mrow + sc_off + c);
    float4 shv = *(const float4*)(mrow + sh_off + c);
    bf16x4_t o;
    o[0] = (__bf16)((v.x - mean) * rstd * (1.f + scv.x) + shv.x);
    o[1] = (__bf16)((v.y - mean) * rstd * (1.f + scv.y) + shv.y);
    o[2] = (__bf16)((v.z - mean) * rstd * (1.f + scv.z) + shv.z);
    o[3] = (__bf16)((v.w - mean) * rstd * (1.f + scv.w) + shv.w);
    *(bf16x4_t*)(out + (size_t)rl * 1024 + c) = o;
}

// ---------------------------------------------------------------------------
// 256x256 bf16 GEMM, round-7 flow + strength-reduced addressing, no lgkm pins.
// 512 threads = 8 waves (2M x 4N); per-wave C 128x64; BK=64; LDS 128KB dbuf.
// Per tile: 4 phases; each phase stages one half of tile t+1 into buf^1
// (strict dbuf -> zero WAR), vmcnt(6) BEFORE the phase barrier certifies
// exactly the half this phase reads, then reads + setprio MFMA cluster.
// NO explicit lgkmcnt: compiler interleaves ds_read retirement with MFMA.
// ---------------------------------------------------------------------------
template <int PM, int PN>
DEV void mfma16(f32x4 (&acc)[8][4], bf16x8_t (&fa)[4][2], bf16x8_t (&fb)[2][2][2]) {
    #pragma unroll
    for (int ks = 0; ks < 2; ++ks)
        #pragma unroll
        for (int mi = 0; mi < 4; ++mi)
            #pragma unroll
            for (int nn = 0; nn < 2; ++nn)
                acc[PM * 4 + mi][PN * 2 + nn] = __builtin_amdgcn_mfma_f32_16x16x32_bf16(
                    fa[mi][ks], fb[PN][nn][ks], acc[PM * 4 + mi][PN * 2 + nn], 0, 0, 0);
}

#define GBAR  __builtin_amdgcn_s_barrier()
#define VM6   asm volatile("s_waitcnt vmcnt(6)" ::: "memory")
#define PRIO1 __builtin_amdgcn_s_setprio(1)
#define PRIO0 __builtin_amdgcn_s_setprio(0)

template <int EPI>
__global__ __launch_bounds__(512)
void gemm256(const __bf16* __restrict__ A, const __bf16* __restrict__ B,
             const float* __restrict__ bias, void* __restrict__ Cout,
             const float* __restrict__ extra, const float* __restrict__ mod,
             int N, int K, int r0, int gx) {
    extern __shared__ __align__(16) char smem[];
    __bf16* lA = (__bf16*)smem;             // [2][256*64]
    __bf16* lB = lA + 2 * 16384;            // [2][256*64]
    const int tid = threadIdx.x, lane = tid & 63, wv = tid >> 6;
    const int wr = wv >> 2, wc = wv & 3;

    // bijective XCD-aware block swizzle (1-D grid)
    const int nwg = gridDim.x;
    const int qq = nwg >> 3, rr8 = nwg & 7;
    const int xcd = blockIdx.x & 7, pos = blockIdx.x >> 3;
    const int nid = (xcd < rr8 ? xcd * (qq + 1) : rr8 * (qq + 1) + (xcd - rr8) * qq) + pos;
    const int bm = (nid / gx) << 8, bn = (nid % gx) << 8;

    f32x4 acc[8][4];
    const f32x4 z4 = {0.f, 0.f, 0.f, 0.f};
    #pragma unroll
    for (int i = 0; i < 8; ++i)
        #pragma unroll
        for (int j = 0; j < 4; ++j) acc[i][j] = z4;

    bf16x8_t fa[4][2], fb[2][2][2];

    // ---- persistent stage pointers (advance +=64 once per tile each) ----
    const int l8  = lane >> 3;
    const int gc8 = ((lane & 7) ^ l8) << 3;
    const int rbw = ((wv & 3) << 3) + ((wv >> 2) << 6);
    const __bf16* gA0 = A + (size_t)(bm +       (wv << 3) + l8) * K + gc8;
    const __bf16* gA1 = A + (size_t)(bm + 128 + (wv << 3) + l8) * K + gc8;
    const __bf16* gA2 = A + (size_t)(bm +  64 + (wv << 3) + l8) * K + gc8;
    const __bf16* gA3 = A + (size_t)(bm + 192 + (wv << 3) + l8) * K + gc8;
    const __bf16* gB0 = B + (size_t)(bn +       rbw + l8) * K + gc8;
    const __bf16* gB1 = B + (size_t)(bn + 128 + rbw + l8) * K + gc8;
    const __bf16* gB2 = B + (size_t)(bn +  32 + rbw + l8) * K + gc8;
    const __bf16* gB3 = B + (size_t)(bn + 160 + rbw + l8) * K + gc8;
    const int dA0 = (wv << 3) * 64, dA1 = (128 + (wv << 3)) * 64;
    const int dA2 = (64 + (wv << 3)) * 64, dA3 = (192 + (wv << 3)) * 64;
    const int dB0 = rbw * 64, dB1 = (128 + rbw) * 64;
    const int dB2 = (32 + rbw) * 64, dB3 = (160 + rbw) * 64;

    auto stA0 = [&](int be) { gload_lds16(gA0, lA + be + dA0); gload_lds16(gA1, lA + be + dA1); gA0 += 64; gA1 += 64; };
    auto stA1 = [&](int be) { gload_lds16(gA2, lA + be + dA2); gload_lds16(gA3, lA + be + dA3); gA2 += 64; gA3 += 64; };
    auto stB0 = [&](int be) { gload_lds16(gB0, lB + be + dB0); gload_lds16(gB1, lB + be + dB1); gB0 += 64; gB1 += 64; };
    auto stB1 = [&](int be) { gload_lds16(gB2, lB + be + dB2); gload_lds16(gB3, lB + be + dB3); gB2 += 64; gB3 += 64; };

    // ---- precomputed ds_read fragment bases ----
    const int swzb = (lane >> 4) ^ (lane & 7);
    const __bf16* aR0 = lA + (wr << 13) + ((lane & 15) << 6) + (swzb << 3);
    const __bf16* aR1 = lA + (wr << 13) + ((lane & 15) << 6) + ((swzb ^ 4) << 3);
    const __bf16* bR0 = lB + (wc << 12) + ((lane & 15) << 6) + (swzb << 3);
    const __bf16* bR1 = lB + (wc << 12) + ((lane & 15) << 6) + ((swzb ^ 4) << 3);

    auto readA = [&](int be, int pm) {
        #pragma unroll
        for (int mi = 0; mi < 4; ++mi) {
            fa[mi][0] = *(const bf16x8_t*)(aR0 + be + pm * 4096 + mi * 1024);
            fa[mi][1] = *(const bf16x8_t*)(aR1 + be + pm * 4096 + mi * 1024);
        }
    };
    auto readB = [&](int be, int pn) {
        #pragma unroll
        for (int ni = 0; ni < 2; ++ni) {
            fb[pn][ni][0] = *(const bf16x8_t*)(bR0 + be + pn * 2048 + ni * 1024);
            fb[pn][ni][1] = *(const bf16x8_t*)(bR1 + be + pn * 2048 + ni * 1024);
        }
    };

    const int nt = K >> 6;
    // prologue: stage tile 0 into buf 0 (order A0, B0, B1, A1)
    stA0(0); stB0(0); stB1(0); stA1(0);

    int be = 0;
    for (int t = 0; t < nt - 1; ++t) {
        // ---- phase 0: stage A0(t+1); certify+read A0,B0(t) ----
        stA0(be ^ 16384);
        VM6; GBAR;
        readA(be, 0); readB(be, 0);
        PRIO1; mfma16<0, 0>(acc, fa, fb); PRIO0;
        // ---- phase 1: stage B0(t+1); certify+read B1(t) ----
        stB0(be ^ 16384);
        VM6; GBAR;
        readB(be, 1);
        PRIO1; mfma16<0, 1>(acc, fa, fb); PRIO0;
        // ---- phase 2: stage B1(t+1); certify+read A1(t) ----
        stB1(be ^ 16384);
        VM6; GBAR;
        readA(be, 1);
        PRIO1; mfma16<1, 0>(acc, fa, fb); PRIO0;
        // ---- phase 3: stage A1(t+1); no reads/barrier ----
        stA1(be ^ 16384);
        PRIO1; mfma16<1, 1>(acc, fa, fb); PRIO0;
        be ^= 16384;
    }
    // ---- tail tile: drain 4 -> 2 -> 0 ----
    asm volatile("s_waitcnt vmcnt(4)" ::: "memory");
    GBAR;
    readA(be, 0); readB(be, 0);
    PRIO1; mfma16<0, 0>(acc, fa, fb); PRIO0;
    asm volatile("s_waitcnt vmcnt(2)" ::: "memory");
    GBAR;
    readB(be, 1);
    PRIO1; mfma16<0, 1>(acc, fa, fb); PRIO0;
    asm volatile("s_waitcnt vmcnt(0)" ::: "memory");
    GBAR;
    readA(be, 1);
    PRIO1; mfma16<1, 0>(acc, fa, fb); mfma16<1, 1>(acc, fa, fb); PRIO0;

    // ---- epilogue ----
    #pragma unroll
    for (int am = 0; am < 8; ++am) {
        #pragma unroll
        for (int j = 0; j < 4; ++j) {
            int m = bm + (wr << 7) + (am << 4) + ((lane >> 4) << 2) + j;
            #pragma unroll
            for (int an = 0; an < 4; ++an) {
                int n = bn + (wc << 6) + (an << 4) + (lane & 15);
                float v = acc[am][an][j] + bias[n];
                if constexpr (EPI == 0) {
                    ((__bf16*)Cout)[(size_t)m * N + n] = (__bf16)v;
                } else if constexpr (EPI == 1) {
                    int mg = m + r0;
                    int tr = win2tok(mg);
                    float g = mod[(mg >> 12) * 6144 + 2048 + n];
                    ((float*)Cout)[(size_t)tr * 1024 + n] = extra[(size_t)tr * 1024 + n] + g * v;
                } else if constexpr (EPI == 2) {
                    ((__bf16*)Cout)[(size_t)m * N + n] = (__bf16)gelu_tanh(v);
                } else {
                    int mg = m + r0;
                    float g = mod[(mg >> 12) * 6144 + 5120 + n];
                    ((float*)Cout)[(size_t)mg * 1024 + n] = extra[(size_t)mg * 1024 + n] + g * v;
                }
            }
        }
    }
}

// ---------------------------------------------------------------------------
// Rel-pos bias tables (LDS-staged rel matrices) — unchanged.
// ---------------------------------------------------------------------------
__global__ __launch_bounds__(256)
void tab_k(const __bf16* __restrict__ qkv, const float* __restrict__ relh,
           const float* __restrict__ relw, __bf16* __restrict__ tab) {
    __shared__ __bf16 lR[2][31][72];
    for (int i = threadIdx.x; i < 1984; i += 256) {
        int row = i >> 6, c = i & 63;
        lR[0][row][c] = (__bf16)relh[i];
        lR[1][row][c] = (__bf16)relw[i];
    }
    __syncthreads();
    const int h = blockIdx.y;
    const int r = threadIdx.x >> 1, half = threadIdx.x & 1;
    const int l = blockIdx.x * 128 + r;
    const int lw = l & 255;
    const int qi = lw >> 4, qj = lw & 15;
    const __bf16* qrow = qkv + (size_t)l * 3072 + h * 64;
    float qq[64];
    #pragma unroll
    for (int c8 = 0; c8 < 8; ++c8) {
        bf16x8_t q8 = *(const bf16x8_t*)(qrow + (c8 << 3));
        #pragma unroll
        for (int e = 0; e < 8; ++e) qq[c8 * 8 + e] = (float)q8[e];
    }
    bf16x8_t oh, ow;
    #pragma unroll
    for (int kk = 0; kk < 8; ++kk) {
        int kg = (half << 3) + kk;
        const __bf16* Rh = &lR[0][qi - kg + 15][0];
        const __bf16* Rw = &lR[1][qj - kg + 15][0];
        float ah = 0.f, aw = 0.f;
        #pragma unroll
        for (int c8 = 0; c8 < 8; ++c8) {
            bf16x8_t r1 = *(const bf16x8_t*)(Rh + (c8 << 3));
            bf16x8_t r2 = *(const bf16x8_t*)(Rw + (c8 << 3));
            #pragma unroll
            for (int e = 0; e < 8; ++e) {
                ah += qq[c8 * 8 + e] * (float)r1[e];
                aw += qq[c8 * 8 + e] * (float)r2[e];
            }
        }
        oh[kk] = (__bf16)ah; ow[kk] = (__bf16)aw;
    }
    size_t idx = ((size_t)(l >> 8) * 16 + h) * 256 + lw;
    *(bf16x8_t*)(tab + idx * 32 + (half << 3))      = oh;
    *(bf16x8_t*)(tab + idx * 32 + 16 + (half << 3)) = ow;
}

// ---------------------------------------------------------------------------
// Window attention — unchanged (passing).
// ---------------------------------------------------------------------------
__global__ __launch_bounds__(256, 3)
void attn_k(const __bf16* __restrict__ qkv, const __bf16* __restrict__ tab,
            __bf16* __restrict__ out) {
    __shared__ __align__(16) __bf16 lP[4][32 * 32];
    __shared__ __align__(16) __bf16 lKt[2][64 * 64];
    __shared__ __align__(16) __bf16 lVt[2][64 * 64];
    __shared__ __align__(16) __bf16 lTab[128 * 32];

    const int blk = blockIdx.x;
    const int winc = blk >> 5, h = (blk >> 1) & 15, qh = blk & 1;
    const int tid = threadIdx.x, lane = tid & 63, wv = tid >> 6;
    const __bf16* base = qkv + (size_t)winc * 256 * 3072 + h * 64;
    const int q0 = qh << 7;

    {
        const __bf16* ts = tab + (((size_t)winc * 16 + h) * 256 + q0) * 32;
        #pragma unroll
        for (int q = 0; q < 2; ++q) {
            int c = (wv << 1) + q;
            gload_lds16(ts + c * 512 + lane * 8, lTab + c * 512);
        }
    }
    bf16x8_t qf[2][2];
    #pragma unroll
    for (int mi = 0; mi < 2; ++mi)
        #pragma unroll
        for (int ks = 0; ks < 2; ++ks) {
            int l = q0 + (wv << 5) + (mi << 4) + (lane & 15);
            qf[mi][ks] = *(const bf16x8_t*)(base + (size_t)l * 3072 + (((ks << 2) + (lane >> 4)) << 3));
        }
    {
        const __bf16* kb = base + 1024;
        #pragma unroll
        for (int q = 0; q < 2; ++q) {
            int c = (wv << 1) + q;
            int kl = (c << 3) + (lane >> 3);
            gload_lds16(kb + (size_t)kl * 3072 + (((lane & 7) ^ (lane >> 3)) << 3),
                        lKt[0] + c * 512);
        }
        const __bf16* vb = base + 2048;
        bf16x8_t a = *(const bf16x8_t*)(vb + (size_t)(tid >> 3) * 3072 + ((tid & 7) << 3));
        bf16x8_t b = *(const bf16x8_t*)(vb + (size_t)(32 + (tid >> 3)) * 3072 + ((tid & 7) << 3));
        int lc = tid & 7;
        #pragma unroll
        for (int e = 0; e < 8; ++e) {
            lVt[0][vt_addr(lc * 8 + e, tid >> 3)]        = a[e];
            lVt[0][vt_addr(lc * 8 + e, 32 + (tid >> 3))] = b[e];
        }
    }
    __syncthreads();

    float twv[2][4];
    #pragma unroll
    for (int mi = 0; mi < 2; ++mi)
        #pragma unroll
        for (int j = 0; j < 4; ++j) {
            int qr = (wv << 5) + (mi << 4) + ((lane >> 4) << 2) + j;
            twv[mi][j] = (float)lTab[qr * 32 + 16 + (lane & 15)];
        }

    const f32x4 z4 = {0.f, 0.f, 0.f, 0.f};
    f32x4 oacc[2][4];
    #pragma unroll
    for (int a = 0; a < 2; ++a)
        #pragma unroll
        for (int b = 0; b < 4; ++b) oacc[a][b] = z4;
    float rsum[2][4];
    #pragma unroll
    for (int a = 0; a < 2; ++a)
        #pragma unroll
        for (int j = 0; j < 4; ++j) rsum[a][j] = 0.f;
    __bf16* lPw = lP[wv];

    int cur = 0;
    for (int kt = 0; kt < 4; ++kt) {
        const bool pre = (kt < 3);
        bf16x8_t v8a, v8b;
        if (pre) {
            const __bf16* kb = base + 1024 + (size_t)(kt + 1) * 64 * 3072;
            #pragma unroll
            for (int q = 0; q < 2; ++q) {
                int c = (wv << 1) + q;
                int kl = (c << 3) + (lane >> 3);
                gload_lds16(kb + (size_t)kl * 3072 + (((lane & 7) ^ (lane >> 3)) << 3),
                            lKt[cur ^ 1] + c * 512);
            }
            const __bf16* vb = base + 2048 + (size_t)(kt + 1) * 64 * 3072;
            v8a = *(const bf16x8_t*)(vb + (size_t)(tid >> 3) * 3072 + ((tid & 7) << 3));
            v8b = *(const bf16x8_t*)(vb + (size_t)(32 + (tid >> 3)) * 3072 + ((tid & 7) << 3));
        }

        f32x4 s[2][4];
        #pragma unroll
        for (int a = 0; a < 2; ++a)
            #pragma unroll
            for (int b = 0; b < 4; ++b) s[a][b] = z4;
        #pragma unroll
        for (int ks = 0; ks < 2; ++ks) {
            bf16x8_t kf[4];
            #pragma unroll
            for (int ni = 0; ni < 4; ++ni)
                kf[ni] = lds_frag(lKt[cur], (ni << 4) + (lane & 15), (ks << 2) + (lane >> 4), 64);
            #pragma unroll
            for (int mi = 0; mi < 2; ++mi)
                #pragma unroll
                for (int ni = 0; ni < 4; ++ni)
                    s[mi][ni] = __builtin_amdgcn_mfma_f32_16x16x32_bf16(qf[mi][ks], kf[ni], s[mi][ni], 0, 0, 0);
        }

        #pragma unroll
        for (int mi = 0; mi < 2; ++mi) {
            #pragma unroll
            for (int j = 0; j < 4; ++j) {
                int qr = (wv << 5) + (mi << 4) + ((lane >> 4) << 2) + j;
                bf16x4_t th4 = *(const bf16x4_t*)(lTab + qr * 32 + (kt << 2));
                float rs = 0.f;
                #pragma unroll
                for (int ni = 0; ni < 4; ++ni) {
                    float p = __expf(s[mi][ni][j] * 0.125f + (float)th4[ni] + twv[mi][j]);
                    s[mi][ni][j] = p;
                    rs += p;
                }
                rsum[mi][j] += rs;
            }
        }

        #pragma unroll
        for (int hf = 0; hf < 2; ++hf) {
            #pragma unroll
            for (int mi = 0; mi < 2; ++mi) {
                #pragma unroll
                for (int j = 0; j < 4; ++j) {
                    int rl = (mi << 4) + ((lane >> 4) << 2) + j;
                    #pragma unroll
                    for (int b = 0; b < 2; ++b) {
                        int col = (b << 4) + (lane & 15);
                        lPw[rl * 32 + ((((col >> 3) ^ ((rl >> 1) & 3)) << 3) | (col & 7))] =
                            (__bf16)s[mi][(hf << 1) + b][j];
                    }
                }
            }
            bf16x8_t pf[2], vf[4];
            #pragma unroll
            for (int mi = 0; mi < 2; ++mi)
                pf[mi] = p_frag(lPw, (mi << 4) + (lane & 15), lane >> 4);
            #pragma unroll
            for (int no = 0; no < 4; ++no) {
                int d = (no << 4) + (lane & 15);
                vf[no] = *(const bf16x8_t*)(lVt[cur] + vt_addr(d, ((hf << 2) + (lane >> 4)) << 3));
            }
            #pragma unroll
            for (int mi = 0; mi < 2; ++mi)
                #pragma unroll
                for (int no = 0; no < 4; ++no)
                    oacc[mi][no] = __builtin_amdgcn_mfma_f32_16x16x32_bf16(pf[mi], vf[no], oacc[mi][no], 0, 0, 0);
        }

        if (pre) {
            int lc = tid & 7;
            #pragma unroll
            for (int e = 0; e < 8; ++e) {
                lVt[cur ^ 1][vt_addr(lc * 8 + e, tid >> 3)]        = v8a[e];
                lVt[cur ^ 1][vt_addr(lc * 8 + e, 32 + (tid >> 3))] = v8b[e];
            }
        }
        __syncthreads();
        cur ^= 1;
    }

    #pragma unroll
    for (int mi = 0; mi < 2; ++mi) {
        #pragma unroll
        for (int j = 0; j < 4; ++j) {
            float rs = rsum[mi][j];
            #pragma unroll
            for (int msk = 1; msk < 16; msk <<= 1) rs += __shfl_xor(rs, msk);
            float inv = 1.f / rs;
            int l = q0 + (wv << 5) + (mi << 4) + ((lane >> 4) << 2) + j;
            #pragma unroll
            for (int no = 0; no < 4; ++no) {
                int col = (no << 4) + (lane & 15);
                out[(size_t)(winc * 256 + l) * 1024 + h * 64 + col] = (__bf16)(oacc[mi][no][j] * inv);
            }
        }
    }
}

// ---------------------------------------------------------------------------
extern "C" void kernel_launch(void* const* d_in, const int* in_sizes, int n_in,
                              void* d_out, int out_size, void* d_ws, size_t ws_size,
                              hipStream_t stream) {
    const float* x      = (const float*)d_in[0];
    const float* c      = (const float*)d_in[1];
    const float* qkv_w  = (const float*)d_in[2];
    const float* qkv_b  = (const float*)d_in[3];
    const float* proj_w = (const float*)d_in[4];
    const float* proj_b = (const float*)d_in[5];
    const float* rel_h  = (const float*)d_in[6];
    const float* rel_w  = (const float*)d_in[7];
    const float* ada_w  = (const float*)d_in[8];
    const float* ada_b  = (const float*)d_in[9];
    const float* fc1_w  = (const float*)d_in[10];
    const float* fc1_b  = (const float*)d_in[11];
    const float* fc2_w  = (const float*)d_in[12];
    const float* fc2_b  = (const float*)d_in[13];
    float* xo = (float*)d_out;

    char* ws = (char*)d_ws;
    const size_t MB = 1ull << 20;
    int CH = 0;
    const int cands[7] = {16384, 8192, 4096, 2048, 1024, 512, 256};
    for (int i = 0; i < 7; ++i)
        if (26 * MB + (size_t)cands[i] * 10240 <= ws_size) { CH = cands[i]; break; }
    if (CH == 0) {
        zero_k<<<65536, 256, 0, stream>>>(xo, 16777216);
        return;
    }

    const int LDSB = 131072;
    hipFuncSetAttribute((const void*)&gemm256<0>, hipFuncAttributeMaxDynamicSharedMemorySize, LDSB);
    hipFuncSetAttribute((const void*)&gemm256<1>, hipFuncAttributeMaxDynamicSharedMemorySize, LDSB);
    hipFuncSetAttribute((const void*)&gemm256<2>, hipFuncAttributeMaxDynamicSharedMemorySize, LDSB);
    hipFuncSetAttribute((const void*)&gemm256<3>, hipFuncAttributeMaxDynamicSharedMemorySize, LDSB);

    const int NCH = 16384 / CH;
    float*  ws_silu = (float*)(ws);
    float*  ws_mod  = (float*)(ws + 65536);
    __bf16* w_qkv   = (__bf16*)(ws + 1 * MB);
    __bf16* w_proj  = (__bf16*)(ws + 7 * MB);
    __bf16* w_fc1   = (__bf16*)(ws + 9 * MB);
    __bf16* w_fc2   = (__bf16*)(ws + 17 * MB);
    __bf16* bufA    = (__bf16*)(ws + 26 * MB);
    __bf16* bufB    = (__bf16*)(ws + 26 * MB + (size_t)CH * 2048);
    __bf16* tabbuf  = bufB + (size_t)CH * 3072;

    silu_k   <<<16,   256, 0, stream>>>(c, ws_silu, 4096);
    mod_gemv <<<6144, 256, 0, stream>>>(ws_silu, ada_w, ada_b, ws_mod);
    conv_bf16<<<3072, 256, 0, stream>>>(qkv_w,  w_qkv,  786432);
    conv_bf16<<<1024, 256, 0, stream>>>(proj_w, w_proj, 262144);
    conv_bf16<<<4096, 256, 0, stream>>>(fc1_w,  w_fc1,  1048576);
    conv_bf16<<<4096, 256, 0, stream>>>(fc2_w,  w_fc2,  1048576);

    const int gy = CH / 256;
    for (int ci = 0; ci < NCH; ++ci) {
        int r0 = ci * CH;
        ln_mod_k<<<CH, 256, 0, stream>>>(x, ws_mod, 0, 1024, bufA, 1, r0);
        gemm256<0><<<12 * gy, 512, LDSB, stream>>>(bufA, w_qkv, qkv_b, bufB,
                                                   nullptr, nullptr, 3072, 1024, r0, 12);
        tab_k<<<dim3(CH / 128, 16), 256, 0, stream>>>(bufB, rel_h, rel_w, tabbuf);
        attn_k<<<(CH / 256) * 32, 256, 0, stream>>>(bufB, tabbuf, bufA);
        gemm256<1><<<4 * gy, 512, LDSB, stream>>>(bufA, w_proj, proj_b, xo,
                                                  x, ws_mod, 1024, 1024, r0, 4);
    }
    for (int ci = 0; ci < NCH; ++ci) {
        int r0 = ci * CH;
        ln_mod_k<<<CH, 256, 0, stream>>>(xo, ws_mod, 3072, 4096, bufA, 0, r0);
        gemm256<2><<<16 * gy, 512, LDSB, stream>>>(bufA, w_fc1, fc1_b, bufB,
                                                   nullptr, nullptr, 4096, 1024, r0, 16);
        gemm256<3><<<4 * gy, 512, LDSB, stream>>>(bufB, w_fc2, fc2_b, xo,
                                                  xo, ws_mod, 1024, 4096, r0, 4);
    }
}

// Round 11
// 631.416 us; speedup vs baseline: 1.0218x; 1.0002x over previous
//
#include <hip/hip_runtime.h>
#include <cstdint>
#include <cstddef>

// ---------------------------------------------------------------------------
// MultiStageDiT round 11: gemm256 with ONE barrier + ONE vmcnt per K-tile
// (was 3-4/tile). Stage of tile t+1 issued immediately after the barrier and
// lands during the ~2500-cycle tile body; waves skew freely within the tile
// so ds_reads of one wave overlap MFMA of another. attn/tab/LN/prep unchanged.
// ---------------------------------------------------------------------------

typedef float  f32x4    __attribute__((ext_vector_type(4)));
typedef __bf16 bf16x8_t __attribute__((ext_vector_type(8)));
typedef __bf16 bf16x4_t __attribute__((ext_vector_type(4)));

#define DEV __device__ __forceinline__

DEV void gload_lds16(const void* g, void* l) {
    auto gp = (const uint32_t __attribute__((address_space(1)))*)(uintptr_t)g;
    auto lp = (uint32_t __attribute__((address_space(3)))*)(uint32_t)(uintptr_t)l;
    __builtin_amdgcn_global_load_lds(gp, lp, 16, 0, 0);
}

// row-major LDS tile, 16B chunks XOR-swizzled by (row&7)
DEV bf16x8_t lds_frag(const __bf16* base, int row, int chunk, int row_elems) {
    return *(const bf16x8_t*)(base + row * row_elems + ((chunk ^ (row & 7)) << 3));
}

// 32-elem-row P tile: XOR key (row>>1)&3
DEV bf16x8_t p_frag(const __bf16* base, int row, int chunk) {
    return *(const bf16x8_t*)(base + row * 32 + ((chunk ^ ((row >> 1) & 3)) << 3));
}

// V^T tile elem address: key (d&7)^((d>>3)&7)
DEV int vt_addr(int d, int k) {
    return d * 64 + ((((k >> 3) ^ (d & 7) ^ ((d >> 3) & 7)) << 3) | (k & 7));
}

DEV float gelu_tanh(float v) {
    float u = 0.7978845608028654f * (v + 0.044715f * v * v * v);
    float e = __expf(2.f * u);
    float th = 1.f - 2.f / (e + 1.f);
    return 0.5f * v * (1.f + th);
}

DEV int win2tok(int r) {
    int nb = r >> 12, wi = (r >> 8) & 15, l = r & 255;
    return (nb << 12) + (wi >> 2) * 1024 + (l >> 4) * 64 + (wi & 3) * 16 + (l & 15);
}

// ---------------------------------------------------------------------------
// prep kernels
// ---------------------------------------------------------------------------
__global__ void silu_k(const float* __restrict__ c, float* __restrict__ o, int n) {
    int i = blockIdx.x * 256 + threadIdx.x;
    if (i < n) { float v = c[i]; o[i] = v / (1.f + __expf(-v)); }
}

__global__ void zero_k(float* o, int n) {
    int i = blockIdx.x * 256 + threadIdx.x;
    if (i < n) o[i] = 0.f;
}

__global__ void conv_bf16(const float* __restrict__ s, __bf16* __restrict__ d, int n4) {
    int i = blockIdx.x * 256 + threadIdx.x;
    if (i < n4) {
        float4 v = ((const float4*)s)[i];
        bf16x4_t o; o[0] = (__bf16)v.x; o[1] = (__bf16)v.y; o[2] = (__bf16)v.z; o[3] = (__bf16)v.w;
        ((bf16x4_t*)d)[i] = o;
    }
}

__global__ __launch_bounds__(256)
void mod_gemv(const float* __restrict__ sc, const float* __restrict__ w,
              const float* __restrict__ b, float* __restrict__ mod) {
    int o = (blockIdx.x << 2) + (threadIdx.x >> 6);
    int lane = threadIdx.x & 63;
    int n = o / 6144, col = o % 6144;
    const float4* wr = (const float4*)(w + (size_t)col * 1024);
    const float4* sr = (const float4*)(sc + n * 1024);
    float acc = 0.f;
    #pragma unroll 4
    for (int i = lane; i < 256; i += 64) {
        float4 a = wr[i], x = sr[i];
        acc += a.x * x.x + a.y * x.y + a.z * x.z + a.w * x.w;
    }
    #pragma unroll
    for (int m = 1; m < 64; m <<= 1) acc += __shfl_xor(acc, m);
    if (lane == 0) mod[o] = acc + b[col];
}

__global__ __launch_bounds__(256)
void ln_mod_k(const float* __restrict__ src, const float* __restrict__ mod,
              int sh_off, int sc_off, __bf16* __restrict__ out, int permute, int r0) {
    int rl = blockIdx.x;
    int r = rl + r0;
    int nb = r >> 12;
    int t = permute ? win2tok(r) : r;
    float4 v = ((const float4*)(src + (size_t)t * 1024))[threadIdx.x];
    float s  = v.x + v.y + v.z + v.w;
    float sq = v.x * v.x + v.y * v.y + v.z * v.z + v.w * v.w;
    #pragma unroll
    for (int m = 1; m < 64; m <<= 1) { s += __shfl_xor(s, m); sq += __shfl_xor(sq, m); }
    __shared__ float ps[4], pq[4];
    int wv = threadIdx.x >> 6, ln = threadIdx.x & 63;
    if (ln == 0) { ps[wv] = s; pq[wv] = sq; }
    __syncthreads();
    s  = ps[0] + ps[1] + ps[2] + ps[3];
    sq = pq[0] + pq[1] + pq[2] + pq[3];
    float mean = s * (1.f / 1024.f);
    float var  = sq * (1.f / 1024.f) - mean * mean;
    float rstd = rsqrtf(var + 1e-6f);
    int c = threadIdx.x << 2;
    const float* mrow = mod + nb * 6144;
    float4 scv = *(const float4*)(mrow + sc_off + c);
    float4 shv = *(const float4*)(mrow + sh_off + c);
    bf16x4_t o;
    o[0] = (__bf16)((v.x - mean) * rstd * (1.f + scv.x) + shv.x);
    o[1] = (__bf16)((v.y - mean) * rstd * (1.f + scv.y) + shv.y);
    o[2] = (__bf16)((v.z - mean) * rstd * (1.f + scv.z) + shv.z);
    o[3] = (__bf16)((v.w - mean) * rstd * (1.f + scv.w) + shv.w);
    *(bf16x4_t*)(out + (size_t)rl * 1024 + c) = o;
}

// ---------------------------------------------------------------------------
// 256x256 bf16 GEMM: 1 barrier + 1 vmcnt per K-tile.
// 512 threads = 8 waves (2M x 4N); per-wave C 128x64; BK=64; LDS 128KB dbuf.
// Per tile: vmcnt(0) (waits prev-tile stage, issued a full tile ago -> ~free),
// s_barrier (separates last tile's reads from this tile's stage overwrite),
// stage all 4 halves of t+1 into buf^1, then reads+MFMA with no further sync
// (per-wave lgkm auto-waits; waves skew for cross-wave read/MFMA overlap).
// ---------------------------------------------------------------------------
template <int PM, int PN>
DEV void mfma16(f32x4 (&acc)[8][4], bf16x8_t (&fa)[4][2], bf16x8_t (&fb)[2][2][2]) {
    #pragma unroll
    for (int ks = 0; ks < 2; ++ks)
        #pragma unroll
        for (int mi = 0; mi < 4; ++mi)
            #pragma unroll
            for (int nn = 0; nn < 2; ++nn)
                acc[PM * 4 + mi][PN * 2 + nn] = __builtin_amdgcn_mfma_f32_16x16x32_bf16(
                    fa[mi][ks], fb[PN][nn][ks], acc[PM * 4 + mi][PN * 2 + nn], 0, 0, 0);
}

#define GBAR  __builtin_amdgcn_s_barrier()
#define PRIO1 __builtin_amdgcn_s_setprio(1)
#define PRIO0 __builtin_amdgcn_s_setprio(0)

template <int EPI>
__global__ __launch_bounds__(512)
void gemm256(const __bf16* __restrict__ A, const __bf16* __restrict__ B,
             const float* __restrict__ bias, void* __restrict__ Cout,
             const float* __restrict__ extra, const float* __restrict__ mod,
             int N, int K, int r0, int gx) {
    extern __shared__ __align__(16) char smem[];
    __bf16* lA = (__bf16*)smem;             // [2][256*64]
    __bf16* lB = lA + 2 * 16384;            // [2][256*64]
    const int tid = threadIdx.x, lane = tid & 63, wv = tid >> 6;
    const int wr = wv >> 2, wc = wv & 3;

    // bijective XCD-aware block swizzle (1-D grid)
    const int nwg = gridDim.x;
    const int qq = nwg >> 3, rr8 = nwg & 7;
    const int xcd = blockIdx.x & 7, pos = blockIdx.x >> 3;
    const int nid = (xcd < rr8 ? xcd * (qq + 1) : rr8 * (qq + 1) + (xcd - rr8) * qq) + pos;
    const int bm = (nid / gx) << 8, bn = (nid % gx) << 8;

    f32x4 acc[8][4];
    const f32x4 z4 = {0.f, 0.f, 0.f, 0.f};
    #pragma unroll
    for (int i = 0; i < 8; ++i)
        #pragma unroll
        for (int j = 0; j < 4; ++j) acc[i][j] = z4;

    bf16x8_t fa[4][2], fb[2][2][2];

    // ---- persistent stage pointers (advance +=64 once per tile each) ----
    const int l8  = lane >> 3;
    const int gc8 = ((lane & 7) ^ l8) << 3;
    const int rbw = ((wv & 3) << 3) + ((wv >> 2) << 6);
    const __bf16* gA0 = A + (size_t)(bm +       (wv << 3) + l8) * K + gc8;
    const __bf16* gA1 = A + (size_t)(bm + 128 + (wv << 3) + l8) * K + gc8;
    const __bf16* gA2 = A + (size_t)(bm +  64 + (wv << 3) + l8) * K + gc8;
    const __bf16* gA3 = A + (size_t)(bm + 192 + (wv << 3) + l8) * K + gc8;
    const __bf16* gB0 = B + (size_t)(bn +       rbw + l8) * K + gc8;
    const __bf16* gB1 = B + (size_t)(bn + 128 + rbw + l8) * K + gc8;
    const __bf16* gB2 = B + (size_t)(bn +  32 + rbw + l8) * K + gc8;
    const __bf16* gB3 = B + (size_t)(bn + 160 + rbw + l8) * K + gc8;
    const int dA0 = (wv << 3) * 64, dA1 = (128 + (wv << 3)) * 64;
    const int dA2 = (64 + (wv << 3)) * 64, dA3 = (192 + (wv << 3)) * 64;
    const int dB0 = rbw * 64, dB1 = (128 + rbw) * 64;
    const int dB2 = (32 + rbw) * 64, dB3 = (160 + rbw) * 64;

    auto stageAll = [&](int be2) {
        gload_lds16(gA0, lA + be2 + dA0); gload_lds16(gA1, lA + be2 + dA1);
        gload_lds16(gB0, lB + be2 + dB0); gload_lds16(gB1, lB + be2 + dB1);
        gload_lds16(gB2, lB + be2 + dB2); gload_lds16(gB3, lB + be2 + dB3);
        gload_lds16(gA2, lA + be2 + dA2); gload_lds16(gA3, lA + be2 + dA3);
        gA0 += 64; gA1 += 64; gA2 += 64; gA3 += 64;
        gB0 += 64; gB1 += 64; gB2 += 64; gB3 += 64;
    };

    // ---- precomputed ds_read fragment bases ----
    const int swzb = (lane >> 4) ^ (lane & 7);
    const __bf16* aR0 = lA + (wr << 13) + ((lane & 15) << 6) + (swzb << 3);
    const __bf16* aR1 = lA + (wr << 13) + ((lane & 15) << 6) + ((swzb ^ 4) << 3);
    const __bf16* bR0 = lB + (wc << 12) + ((lane & 15) << 6) + (swzb << 3);
    const __bf16* bR1 = lB + (wc << 12) + ((lane & 15) << 6) + ((swzb ^ 4) << 3);

    auto readA = [&](int be2, int pm) {
        #pragma unroll
        for (int mi = 0; mi < 4; ++mi) {
            fa[mi][0] = *(const bf16x8_t*)(aR0 + be2 + pm * 4096 + mi * 1024);
            fa[mi][1] = *(const bf16x8_t*)(aR1 + be2 + pm * 4096 + mi * 1024);
        }
    };
    auto readB = [&](int be2, int pn) {
        #pragma unroll
        for (int ni = 0; ni < 2; ++ni) {
            fb[pn][ni][0] = *(const bf16x8_t*)(bR0 + be2 + pn * 2048 + ni * 1024);
            fb[pn][ni][1] = *(const bf16x8_t*)(bR1 + be2 + pn * 2048 + ni * 1024);
        }
    };

    const int nt = K >> 6;
    stageAll(0);                         // prologue: tile 0 -> buf 0

    int be = 0;
    for (int t = 0; t < nt; ++t) {
        asm volatile("s_waitcnt vmcnt(0)" ::: "memory");   // prev stage landed (issued a full tile ago)
        GBAR;                                              // all waves done reading buf being overwritten
        if (t + 1 < nt) stageAll(be ^ 16384);
        readA(be, 0); readB(be, 0); readB(be, 1);
        PRIO1; mfma16<0, 0>(acc, fa, fb); mfma16<0, 1>(acc, fa, fb); PRIO0;
        readA(be, 1);
        PRIO1; mfma16<1, 0>(acc, fa, fb); mfma16<1, 1>(acc, fa, fb); PRIO0;
        be ^= 16384;
    }

    // ---- epilogue ----
    #pragma unroll
    for (int am = 0; am < 8; ++am) {
        #pragma unroll
        for (int j = 0; j < 4; ++j) {
            int m = bm + (wr << 7) + (am << 4) + ((lane >> 4) << 2) + j;
            #pragma unroll
            for (int an = 0; an < 4; ++an) {
                int n = bn + (wc << 6) + (an << 4) + (lane & 15);
                float v = acc[am][an][j] + bias[n];
                if constexpr (EPI == 0) {
                    ((__bf16*)Cout)[(size_t)m * N + n] = (__bf16)v;
                } else if constexpr (EPI == 1) {
                    int mg = m + r0;
                    int tr = win2tok(mg);
                    float g = mod[(mg >> 12) * 6144 + 2048 + n];
                    ((float*)Cout)[(size_t)tr * 1024 + n] = extra[(size_t)tr * 1024 + n] + g * v;
                } else if constexpr (EPI == 2) {
                    ((__bf16*)Cout)[(size_t)m * N + n] = (__bf16)gelu_tanh(v);
                } else {
                    int mg = m + r0;
                    float g = mod[(mg >> 12) * 6144 + 5120 + n];
                    ((float*)Cout)[(size_t)mg * 1024 + n] = extra[(size_t)mg * 1024 + n] + g * v;
                }
            }
        }
    }
}

// ---------------------------------------------------------------------------
// Rel-pos bias tables (LDS-staged rel matrices) — unchanged.
// ---------------------------------------------------------------------------
__global__ __launch_bounds__(256)
void tab_k(const __bf16* __restrict__ qkv, const float* __restrict__ relh,
           const float* __restrict__ relw, __bf16* __restrict__ tab) {
    __shared__ __bf16 lR[2][31][72];
    for (int i = threadIdx.x; i < 1984; i += 256) {
        int row = i >> 6, c = i & 63;
        lR[0][row][c] = (__bf16)relh[i];
        lR[1][row][c] = (__bf16)relw[i];
    }
    __syncthreads();
    const int h = blockIdx.y;
    const int r = threadIdx.x >> 1, half = threadIdx.x & 1;
    const int l = blockIdx.x * 128 + r;
    const int lw = l & 255;
    const int qi = lw >> 4, qj = lw & 15;
    const __bf16* qrow = qkv + (size_t)l * 3072 + h * 64;
    float qq[64];
    #pragma unroll
    for (int c8 = 0; c8 < 8; ++c8) {
        bf16x8_t q8 = *(const bf16x8_t*)(qrow + (c8 << 3));
        #pragma unroll
        for (int e = 0; e < 8; ++e) qq[c8 * 8 + e] = (float)q8[e];
    }
    bf16x8_t oh, ow;
    #pragma unroll
    for (int kk = 0; kk < 8; ++kk) {
        int kg = (half << 3) + kk;
        const __bf16* Rh = &lR[0][qi - kg + 15][0];
        const __bf16* Rw = &lR[1][qj - kg + 15][0];
        float ah = 0.f, aw = 0.f;
        #pragma unroll
        for (int c8 = 0; c8 < 8; ++c8) {
            bf16x8_t r1 = *(const bf16x8_t*)(Rh + (c8 << 3));
            bf16x8_t r2 = *(const bf16x8_t*)(Rw + (c8 << 3));
            #pragma unroll
            for (int e = 0; e < 8; ++e) {
                ah += qq[c8 * 8 + e] * (float)r1[e];
                aw += qq[c8 * 8 + e] * (float)r2[e];
            }
        }
        oh[kk] = (__bf16)ah; ow[kk] = (__bf16)aw;
    }
    size_t idx = ((size_t)(l >> 8) * 16 + h) * 256 + lw;
    *(bf16x8_t*)(tab + idx * 32 + (half << 3))      = oh;
    *(bf16x8_t*)(tab + idx * 32 + 16 + (half << 3)) = ow;
}

// ---------------------------------------------------------------------------
// Window attention — unchanged (passing).
// ---------------------------------------------------------------------------
__global__ __launch_bounds__(256, 3)
void attn_k(const __bf16* __restrict__ qkv, const __bf16* __restrict__ tab,
            __bf16* __restrict__ out) {
    __shared__ __align__(16) __bf16 lP[4][32 * 32];
    __shared__ __align__(16) __bf16 lKt[2][64 * 64];
    __shared__ __align__(16) __bf16 lVt[2][64 * 64];
    __shared__ __align__(16) __bf16 lTab[128 * 32];

    const int blk = blockIdx.x;
    const int winc = blk >> 5, h = (blk >> 1) & 15, qh = blk & 1;
    const int tid = threadIdx.x, lane = tid & 63, wv = tid >> 6;
    const __bf16* base = qkv + (size_t)winc * 256 * 3072 + h * 64;
    const int q0 = qh << 7;

    {
        const __bf16* ts = tab + (((size_t)winc * 16 + h) * 256 + q0) * 32;
        #pragma unroll
        for (int q = 0; q < 2; ++q) {
            int c = (wv << 1) + q;
            gload_lds16(ts + c * 512 + lane * 8, lTab + c * 512);
        }
    }
    bf16x8_t qf[2][2];
    #pragma unroll
    for (int mi = 0; mi < 2; ++mi)
        #pragma unroll
        for (int ks = 0; ks < 2; ++ks) {
            int l = q0 + (wv << 5) + (mi << 4) + (lane & 15);
            qf[mi][ks] = *(const bf16x8_t*)(base + (size_t)l * 3072 + (((ks << 2) + (lane >> 4)) << 3));
        }
    {
        const __bf16* kb = base + 1024;
        #pragma unroll
        for (int q = 0; q < 2; ++q) {
            int c = (wv << 1) + q;
            int kl = (c << 3) + (lane >> 3);
            gload_lds16(kb + (size_t)kl * 3072 + (((lane & 7) ^ (lane >> 3)) << 3),
                        lKt[0] + c * 512);
        }
        const __bf16* vb = base + 2048;
        bf16x8_t a = *(const bf16x8_t*)(vb + (size_t)(tid >> 3) * 3072 + ((tid & 7) << 3));
        bf16x8_t b = *(const bf16x8_t*)(vb + (size_t)(32 + (tid >> 3)) * 3072 + ((tid & 7) << 3));
        int lc = tid & 7;
        #pragma unroll
        for (int e = 0; e < 8; ++e) {
            lVt[0][vt_addr(lc * 8 + e, tid >> 3)]        = a[e];
            lVt[0][vt_addr(lc * 8 + e, 32 + (tid >> 3))] = b[e];
        }
    }
    __syncthreads();

    float twv[2][4];
    #pragma unroll
    for (int mi = 0; mi < 2; ++mi)
        #pragma unroll
        for (int j = 0; j < 4; ++j) {
            int qr = (wv << 5) + (mi << 4) + ((lane >> 4) << 2) + j;
            twv[mi][j] = (float)lTab[qr * 32 + 16 + (lane & 15)];
        }

    const f32x4 z4 = {0.f, 0.f, 0.f, 0.f};
    f32x4 oacc[2][4];
    #pragma unroll
    for (int a = 0; a < 2; ++a)
        #pragma unroll
        for (int b = 0; b < 4; ++b) oacc[a][b] = z4;
    float rsum[2][4];
    #pragma unroll
    for (int a = 0; a < 2; ++a)
        #pragma unroll
        for (int j = 0; j < 4; ++j) rsum[a][j] = 0.f;
    __bf16* lPw = lP[wv];

    int cur = 0;
    for (int kt = 0; kt < 4; ++kt) {
        const bool pre = (kt < 3);
        bf16x8_t v8a, v8b;
        if (pre) {
            const __bf16* kb = base + 1024 + (size_t)(kt + 1) * 64 * 3072;
            #pragma unroll
            for (int q = 0; q < 2; ++q) {
                int c = (wv << 1) + q;
                int kl = (c << 3) + (lane >> 3);
                gload_lds16(kb + (size_t)kl * 3072 + (((lane & 7) ^ (lane >> 3)) << 3),
                            lKt[cur ^ 1] + c * 512);
            }
            const __bf16* vb = base + 2048 + (size_t)(kt + 1) * 64 * 3072;
            v8a = *(const bf16x8_t*)(vb + (size_t)(tid >> 3) * 3072 + ((tid & 7) << 3));
            v8b = *(const bf16x8_t*)(vb + (size_t)(32 + (tid >> 3)) * 3072 + ((tid & 7) << 3));
        }

        f32x4 s[2][4];
        #pragma unroll
        for (int a = 0; a < 2; ++a)
            #pragma unroll
            for (int b = 0; b < 4; ++b) s[a][b] = z4;
        #pragma unroll
        for (int ks = 0; ks < 2; ++ks) {
            bf16x8_t kf[4];
            #pragma unroll
            for (int ni = 0; ni < 4; ++ni)
                kf[ni] = lds_frag(lKt[cur], (ni << 4) + (lane & 15), (ks << 2) + (lane >> 4), 64);
            #pragma unroll
            for (int mi = 0; mi < 2; ++mi)
                #pragma unroll
                for (int ni = 0; ni < 4; ++ni)
                    s[mi][ni] = __builtin_amdgcn_mfma_f32_16x16x32_bf16(qf[mi][ks], kf[ni], s[mi][ni], 0, 0, 0);
        }

        #pragma unroll
        for (int mi = 0; mi < 2; ++mi) {
            #pragma unroll
            for (int j = 0; j < 4; ++j) {
                int qr = (wv << 5) + (mi << 4) + ((lane >> 4) << 2) + j;
                bf16x4_t th4 = *(const bf16x4_t*)(lTab + qr * 32 + (kt << 2));
                float rs = 0.f;
                #pragma unroll
                for (int ni = 0; ni < 4; ++ni) {
                    float p = __expf(s[mi][ni][j] * 0.125f + (float)th4[ni] + twv[mi][j]);
                    s[mi][ni][j] = p;
                    rs += p;
                }
                rsum[mi][j] += rs;
            }
        }

        #pragma unroll
        for (int hf = 0; hf < 2; ++hf) {
            #pragma unroll
            for (int mi = 0; mi < 2; ++mi) {
                #pragma unroll
                for (int j = 0; j < 4; ++j) {
                    int rl = (mi << 4) + ((lane >> 4) << 2) + j;
                    #pragma unroll
                    for (int b = 0; b < 2; ++b) {
                        int col = (b << 4) + (lane & 15);
                        lPw[rl * 32 + ((((col >> 3) ^ ((rl >> 1) & 3)) << 3) | (col & 7))] =
                            (__bf16)s[mi][(hf << 1) + b][j];
                    }
                }
            }
            bf16x8_t pf[2], vf[4];
            #pragma unroll
            for (int mi = 0; mi < 2; ++mi)
                pf[mi] = p_frag(lPw, (mi << 4) + (lane & 15), lane >> 4);
            #pragma unroll
            for (int no = 0; no < 4; ++no) {
                int d = (no << 4) + (lane & 15);
                vf[no] = *(const bf16x8_t*)(lVt[cur] + vt_addr(d, ((hf << 2) + (lane >> 4)) << 3));
            }
            #pragma unroll
            for (int mi = 0; mi < 2; ++mi)
                #pragma unroll
                for (int no = 0; no < 4; ++no)
                    oacc[mi][no] = __builtin_amdgcn_mfma_f32_16x16x32_bf16(pf[mi], vf[no], oacc[mi][no], 0, 0, 0);
        }

        if (pre) {
            int lc = tid & 7;
            #pragma unroll
            for (int e = 0; e < 8; ++e) {
                lVt[cur ^ 1][vt_addr(lc * 8 + e, tid >> 3)]        = v8a[e];
                lVt[cur ^ 1][vt_addr(lc * 8 + e, 32 + (tid >> 3))] = v8b[e];
            }
        }
        __syncthreads();
        cur ^= 1;
    }

    #pragma unroll
    for (int mi = 0; mi < 2; ++mi) {
        #pragma unroll
        for (int j = 0; j < 4; ++j) {
            float rs = rsum[mi][j];
            #pragma unroll
            for (int msk = 1; msk < 16; msk <<= 1) rs += __shfl_xor(rs, msk);
            float inv = 1.f / rs;
            int l = q0 + (wv << 5) + (mi << 4) + ((lane >> 4) << 2) + j;
            #pragma unroll
            for (int no = 0; no < 4; ++no) {
                int col = (no << 4) + (lane & 15);
                out[(size_t)(winc * 256 + l) * 1024 + h * 64 + col] = (__bf16)(oacc[mi][no][j] * inv);
            }
        }
    }
}

// ---------------------------------------------------------------------------
extern "C" void kernel_launch(void* const* d_in, const int* in_sizes, int n_in,
                              void* d_out, int out_size, void* d_ws, size_t ws_size,
                              hipStream_t stream) {
    const float* x      = (const float*)d_in[0];
    const float* c      = (const float*)d_in[1];
    const float* qkv_w  = (const float*)d_in[2];
    const float* qkv_b  = (const float*)d_in[3];
    const float* proj_w = (const float*)d_in[4];
    const float* proj_b = (const float*)d_in[5];
    const float* rel_h  = (const float*)d_in[6];
    const float* rel_w  = (const float*)d_in[7];
    const float* ada_w  = (const float*)d_in[8];
    const float* ada_b  = (const float*)d_in[9];
    const float* fc1_w  = (const float*)d_in[10];
    const float* fc1_b  = (const float*)d_in[11];
    const float* fc2_w  = (const float*)d_in[12];
    const float* fc2_b  = (const float*)d_in[13];
    float* xo = (float*)d_out;

    char* ws = (char*)d_ws;
    const size_t MB = 1ull << 20;
    int CH = 0;
    const int cands[7] = {16384, 8192, 4096, 2048, 1024, 512, 256};
    for (int i = 0; i < 7; ++i)
        if (26 * MB + (size_t)cands[i] * 10240 <= ws_size) { CH = cands[i]; break; }
    if (CH == 0) {
        zero_k<<<65536, 256, 0, stream>>>(xo, 16777216);
        return;
    }

    const int LDSB = 131072;
    hipFuncSetAttribute((const void*)&gemm256<0>, hipFuncAttributeMaxDynamicSharedMemorySize, LDSB);
    hipFuncSetAttribute((const void*)&gemm256<1>, hipFuncAttributeMaxDynamicSharedMemorySize, LDSB);
    hipFuncSetAttribute((const void*)&gemm256<2>, hipFuncAttributeMaxDynamicSharedMemorySize, LDSB);
    hipFuncSetAttribute((const void*)&gemm256<3>, hipFuncAttributeMaxDynamicSharedMemorySize, LDSB);

    const int NCH = 16384 / CH;
    float*  ws_silu = (float*)(ws);
    float*  ws_mod  = (float*)(ws + 65536);
    __bf16* w_qkv   = (__bf16*)(ws + 1 * MB);
    __bf16* w_proj  = (__bf16*)(ws + 7 * MB);
    __bf16* w_fc1   = (__bf16*)(ws + 9 * MB);
    __bf16* w_fc2   = (__bf16*)(ws + 17 * MB);
    __bf16* bufA    = (__bf16*)(ws + 26 * MB);
    __bf16* bufB    = (__bf16*)(ws + 26 * MB + (size_t)CH * 2048);
    __bf16* tabbuf  = bufB + (size_t)CH * 3072;

    silu_k   <<<16,   256, 0, stream>>>(c, ws_silu, 4096);
    mod_gemv <<<6144, 256, 0, stream>>>(ws_silu, ada_w, ada_b, ws_mod);
    conv_bf16<<<3072, 256, 0, stream>>>(qkv_w,  w_qkv,  786432);
    conv_bf16<<<1024, 256, 0, stream>>>(proj_w, w_proj, 262144);
    conv_bf16<<<4096, 256, 0, stream>>>(fc1_w,  w_fc1,  1048576);
    conv_bf16<<<4096, 256, 0, stream>>>(fc2_w,  w_fc2,  1048576);

    const int gy = CH / 256;
    for (int ci = 0; ci < NCH; ++ci) {
        int r0 = ci * CH;
        ln_mod_k<<<CH, 256, 0, stream>>>(x, ws_mod, 0, 1024, bufA, 1, r0);
        gemm256<0><<<12 * gy, 512, LDSB, stream>>>(bufA, w_qkv, qkv_b, bufB,
                                                   nullptr, nullptr, 3072, 1024, r0, 12);
        tab_k<<<dim3(CH / 128, 16), 256, 0, stream>>>(bufB, rel_h, rel_w, tabbuf);
        attn_k<<<(CH / 256) * 32, 256, 0, stream>>>(bufB, tabbuf, bufA);
        gemm256<1><<<4 * gy, 512, LDSB, stream>>>(bufA, w_proj, proj_b, xo,
                                                  x, ws_mod, 1024, 1024, r0, 4);
    }
    for (int ci = 0; ci < NCH; ++ci) {
        int r0 = ci * CH;
        ln_mod_k<<<CH, 256, 0, stream>>>(xo, ws_mod, 3072, 4096, bufA, 0, r0);
        gemm256<2><<<16 * gy, 512, LDSB, stream>>>(bufA, w_fc1, fc1_b, bufB,
                                                   nullptr, nullptr, 4096, 1024, r0, 16);
        gemm256<3><<<4 * gy, 512, LDSB, stream>>>(bufB, w_fc2, fc2_b, xo,
                                                  xo, ws_mod, 1024, 4096, r0, 4);
    }
}